// Round 8
// baseline (621.050 us; speedup 1.0000x reference)
//
#include <hip/hip_runtime.h>
#include <hip/hip_bf16.h>
#include <math.h>

#define NP_N 4096
#define NH_N 4096
#define D_N 512
#define BERT_N 768
#define H_N 4
#define B_N 32
#define SCL2 0.12754245006257576f   // log2(e)/sqrt(128), folded into Wq/bq

typedef __attribute__((ext_vector_type(8))) short short8;
typedef __attribute__((ext_vector_type(4))) float f32x4;
typedef __attribute__((ext_vector_type(4))) unsigned short ush4;
typedef __attribute__((ext_vector_type(4))) unsigned int uivec4;
typedef unsigned short ushort_t;

__device__ __forceinline__ void gl_lds16(const void* g, void* l) {
    __builtin_amdgcn_global_load_lds((const __attribute__((address_space(1))) void*)g,
                                     (__attribute__((address_space(3))) void*)l, 16, 0, 0);
}
__device__ __forceinline__ unsigned short f2bu(float f) {
    __hip_bfloat16 b = __float2bfloat16(f);
    return *reinterpret_cast<unsigned short*>(&b);
}
__device__ __forceinline__ float b2f(unsigned short u) {
    union { unsigned int i; float f; } x; x.i = ((unsigned int)u) << 16; return x.f;
}
__device__ __forceinline__ unsigned int pkbf(float a, float b) {
    union { __hip_bfloat162 h; unsigned int u; } x;
    x.h.x = __float2bfloat16(a);
    x.h.y = __float2bfloat16(b);
    return x.u;
}
__device__ __forceinline__ unsigned int sxor(unsigned int v, int m) {
    return (unsigned int)__shfl_xor((int)v, m);
}

// Build PV A-fragment (32 keys) from QK^T C-layout pairs u (keys 0-15 block)
// and v (keys 16-31 block). Verified in rounds 3-7.
__device__ __forceinline__ short8 mkfrag(uint2 u, uint2 v, bool hi, bool godd) {
    unsigned ux32 = sxor(u.x, 32), uy32 = sxor(u.y, 32);
    unsigned vx32 = sxor(v.x, 32), vy32 = sxor(v.y, 32);
    unsigned ax = hi ? vx32 : u.x, bx = hi ? v.x : ux32;
    unsigned ay = hi ? vy32 : u.y, by = hi ? v.y : uy32;
    unsigned sbx = sxor(bx, 16), sax = sxor(ax, 16);
    unsigned sby = sxor(by, 16), say = sxor(ay, 16);
    uivec4 w;
    w.x = godd ? sbx : ax;
    w.y = godd ? sby : ay;
    w.z = godd ? bx : sax;
    w.w = godd ? by : say;
    return __builtin_bit_cast(short8, w);
}

// =========================== convert + transpose ===========================
#define EW_BLOCKS 512
__global__ __launch_bounds__(256) void convert_all(
    const float* __restrict__ ctx_h, const float* __restrict__ ctx_p,
    const float* __restrict__ lhs_p,
    const float* __restrict__ Wq, const float* __restrict__ Wk,
    const float* __restrict__ Wv, const float* __restrict__ W1,
    const float* __restrict__ bq, const float* __restrict__ bk,
    ushort_t* __restrict__ ctxp_bf, ushort_t* __restrict__ lhsp_bf,
    ushort_t* __restrict__ feats,
    ushort_t* __restrict__ Wqt, ushort_t* __restrict__ Wkt,
    ushort_t* __restrict__ Wvt, ushort_t* __restrict__ W1t,
    float* __restrict__ bqp, float* __restrict__ bkp)
{
    const int bid = blockIdx.x, t = threadIdx.x;
    if (bid < EW_BLOCKS) {
        const long N0 = 524288, N1 = 1048576, TOT = 1835008;  // float4 counts
        for (long i = (long)bid * 256 + t; i < TOT; i += (long)EW_BLOCKS * 256) {
            float4 v; ush4 o;
            if (i < N0) {
                long k = i;
                v = ((const float4*)ctx_h)[k];
                o[0] = f2bu(v.x); o[1] = f2bu(v.y); o[2] = f2bu(v.z); o[3] = f2bu(v.w);
                long n = k >> 7, c4 = k & 127;
                ((ush4*)feats)[n * 320 + c4] = o;      // feats[:, 0:512]
            } else if (i < N1) {
                long k = i - N0;
                v = ((const float4*)ctx_p)[k];
                o[0] = f2bu(v.x); o[1] = f2bu(v.y); o[2] = f2bu(v.z); o[3] = f2bu(v.w);
                ((ush4*)ctxp_bf)[k] = o;
            } else {
                long k = i - N1;
                v = ((const float4*)lhs_p)[k];
                o[0] = f2bu(v.x); o[1] = f2bu(v.y); o[2] = f2bu(v.z); o[3] = f2bu(v.w);
                ((ush4*)lhsp_bf)[k] = o;
            }
        }
        if (bid == 0) {
            for (int n = t; n < 512; n += 256) {
                int np = (n & 3) * 128 + (n >> 2);
                bqp[np] = bq[n] * SCL2;
                bkp[np] = bk[n];
            }
        }
        return;
    }
    int tb = bid - EW_BLOCKS;
    const float* src; ushort_t* dst; int K, N, tile, perm; float wscl;
    if (tb < 64)       { src = Wq; dst = Wqt; K = 512;  N = 512; tile = tb;       perm = 1; wscl = SCL2; }
    else if (tb < 128) { src = Wk; dst = Wkt; K = 512;  N = 512; tile = tb - 64;  perm = 1; wscl = 1.f; }
    else if (tb < 272) { src = Wv; dst = Wvt; K = 768;  N = 768; tile = tb - 128; perm = 0; wscl = 1.f; }
    else               { src = W1; dst = W1t; K = 1280; N = 256; tile = tb - 272; perm = 0; wscl = 1.f; }
    int ntn = N >> 6;
    int k0 = (tile / ntn) * 64, n0 = (tile % ntn) * 64;
    __shared__ float tl[64][65];
#pragma unroll
    for (int i = 0; i < 16; i++) {
        int idx = t + i * 256; int r = idx >> 6, c = idx & 63;
        tl[r][c] = src[(size_t)(k0 + r) * N + n0 + c];
    }
    __syncthreads();
#pragma unroll
    for (int i = 0; i < 16; i++) {
        int idx = t + i * 256; int r = idx >> 6, c = idx & 63;
        int n = n0 + r;
        int nr = perm ? ((n & 3) * 128 + (n >> 2)) : n;
        dst[(size_t)nr * K + k0 + c] = f2bu(tl[c][r] * wscl);
    }
}

// ================ fused Q/K/V projection GEMMs (one launch) =================
__global__ __launch_bounds__(256) void gemm_qkv(
    const ushort_t* __restrict__ feats, const ushort_t* __restrict__ ctxp,
    const ushort_t* __restrict__ Wqt, const ushort_t* __restrict__ Wkt,
    const ushort_t* __restrict__ Wvt, const ushort_t* __restrict__ lhsp,
    const float* __restrict__ bqp, const float* __restrict__ bkp,
    const float* __restrict__ bv,
    ushort_t* __restrict__ Qb, ushort_t* __restrict__ Kb,
    ushort_t* __restrict__ Vtb)
{
    int b = blockIdx.x;
    const ushort_t *A, *Bt; const float* bias; ushort_t* C;
    int lda, N, K, m0, n0, bias_row;
    if (b < 256) {          // Q: M=4096, N=512, K=512
        A = feats; lda = 1280; Bt = Wqt; bias = bqp; C = Qb;
        N = 512; K = 512; bias_row = 0;
        n0 = (b & 7) * 64; m0 = (b >> 3) * 128;
    } else if (b < 512) {   // K
        b -= 256;
        A = ctxp; lda = 512; Bt = Wkt; bias = bkp; C = Kb;
        N = 512; K = 512; bias_row = 0;
        n0 = (b & 7) * 64; m0 = (b >> 3) * 128;
    } else {                // V^T: M=768 (Wvt rows), N=4096, K=768
        b -= 512;
        A = Wvt; lda = 768; Bt = lhsp; bias = bv; C = Vtb;
        N = 4096; K = 768; bias_row = 1;
        n0 = (b & 63) * 64; m0 = (b >> 6) * 128;
    }
    const int nsteps = K >> 6;

    __shared__ ushort_t As[2][128 * 64];
    __shared__ ushort_t Bs[2][64 * 64];
    const int t = threadIdx.x, w = t >> 6, lane = t & 63;
    const int lq = lane & 15, g = lane >> 4;
    const int wm = w >> 1, wn = w & 1;

    f32x4 acc[4][2] = {};

    auto STAGE = [&](int buf, int k0) {
#pragma unroll
        for (int jj = 0; jj < 4; jj++) {
            int j = w * 4 + jj;
            int r = j * 8 + (lane >> 3);
            int c = (lane & 7) * 16;
            int cs = c ^ ((r & 7) << 4);
            gl_lds16((const char*)A + ((size_t)(m0 + r) * lda + k0) * 2 + cs,
                     (void*)&As[buf][j * 512]);
        }
#pragma unroll
        for (int jj = 0; jj < 2; jj++) {
            int j = w * 2 + jj;
            int r = j * 8 + (lane >> 3);
            int c = (lane & 7) * 16;
            int cs = c ^ ((r & 7) << 4);
            gl_lds16((const char*)Bt + ((size_t)(n0 + r) * K + k0) * 2 + cs,
                     (void*)&Bs[buf][j * 512]);
        }
    };

    STAGE(0, 0);
    asm volatile("s_waitcnt vmcnt(0)" ::: "memory");
    __builtin_amdgcn_s_barrier();
    int cur = 0;
    for (int s = 0; s < nsteps; s++) {
        if (s + 1 < nsteps) STAGE(cur ^ 1, (s + 1) * 64);
        const char* Ab = (const char*)&As[cur][0];
        const char* Bb = (const char*)&Bs[cur][0];
        const int swz = (lq & 7) << 4;
        short8 af[4][2], bfr[2][2];
#pragma unroll
        for (int mf = 0; mf < 4; mf++) {
            int r = wm * 64 + mf * 16 + lq;
#pragma unroll
            for (int ks = 0; ks < 2; ks++)
                af[mf][ks] = *(const short8*)(Ab + r * 128 + ((ks * 64 + g * 16) ^ swz));
        }
#pragma unroll
        for (int nf = 0; nf < 2; nf++) {
            int r = wn * 32 + nf * 16 + lq;
#pragma unroll
            for (int ks = 0; ks < 2; ks++)
                bfr[nf][ks] = *(const short8*)(Bb + r * 128 + ((ks * 64 + g * 16) ^ swz));
        }
        __builtin_amdgcn_s_setprio(1);
#pragma unroll
        for (int mf = 0; mf < 4; mf++)
#pragma unroll
            for (int nf = 0; nf < 2; nf++)
#pragma unroll
                for (int ks = 0; ks < 2; ks++)
                    acc[mf][nf] = __builtin_amdgcn_mfma_f32_16x16x32_bf16(
                        af[mf][ks], bfr[nf][ks], acc[mf][nf], 0, 0, 0);
        __builtin_amdgcn_s_setprio(0);
        asm volatile("s_waitcnt vmcnt(0)" ::: "memory");
        __builtin_amdgcn_s_barrier();
        cur ^= 1;
    }

#pragma unroll
    for (int mf = 0; mf < 4; mf++) {
#pragma unroll
        for (int nf = 0; nf < 2; nf++) {
            int ncol = n0 + wn * 32 + nf * 16 + lq;
            float bcol = bias_row ? 0.f : bias[ncol];
#pragma unroll
            for (int j = 0; j < 4; j++) {
                int mrow = m0 + wm * 64 + mf * 16 + 4 * g + j;
                float v = acc[mf][nf][j] + (bias_row ? bias[mrow] : bcol);
                C[(size_t)mrow * N + ncol] = f2bu(v);
            }
        }
    }
}

// ======================= MLP1 GEMM (64x64, GELU) ============================
template<int TM, int TN>
__global__ __launch_bounds__(256) void gemm_mlp1(
    const ushort_t* __restrict__ A, int lda, const ushort_t* __restrict__ Bt,
    const float* __restrict__ bias, ushort_t* __restrict__ C,
    int M, int N, int K)
{
    constexpr int MF = TM / 32, NF = TN / 32;
    __shared__ ushort_t As[2][TM * 64];
    __shared__ ushort_t Bs[2][TN * 64];
    const int t = threadIdx.x, w = t >> 6, lane = t & 63;
    const int lq = lane & 15, g = lane >> 4;
    const int wm = w >> 1, wn = w & 1;
    const int n0 = blockIdx.x * TN, m0 = blockIdx.y * TM;
    const int nsteps = K >> 6;

    f32x4 acc[MF][NF] = {};

    auto STAGE = [&](int buf, int k0) {
#pragma unroll
        for (int jj = 0; jj < TM / 32; jj++) {
            int j = w * (TM / 32) + jj;
            int r = j * 8 + (lane >> 3);
            int c = (lane & 7) * 16;
            int cs = c ^ ((r & 7) << 4);
            gl_lds16((const char*)A + ((size_t)(m0 + r) * lda + k0) * 2 + cs,
                     (void*)&As[buf][j * 512]);
        }
#pragma unroll
        for (int jj = 0; jj < TN / 32; jj++) {
            int j = w * (TN / 32) + jj;
            int r = j * 8 + (lane >> 3);
            int c = (lane & 7) * 16;
            int cs = c ^ ((r & 7) << 4);
            gl_lds16((const char*)Bt + ((size_t)(n0 + r) * K + k0) * 2 + cs,
                     (void*)&Bs[buf][j * 512]);
        }
    };

    STAGE(0, 0);
    asm volatile("s_waitcnt vmcnt(0)" ::: "memory");
    __builtin_amdgcn_s_barrier();
    int cur = 0;
    for (int s = 0; s < nsteps; s++) {
        if (s + 1 < nsteps) STAGE(cur ^ 1, (s + 1) * 64);
        const char* Ab = (const char*)&As[cur][0];
        const char* Bb = (const char*)&Bs[cur][0];
        const int swz = (lq & 7) << 4;
        short8 af[MF][2], bfr[NF][2];
#pragma unroll
        for (int mf = 0; mf < MF; mf++) {
            int r = wm * (TM / 2) + mf * 16 + lq;
#pragma unroll
            for (int ks = 0; ks < 2; ks++)
                af[mf][ks] = *(const short8*)(Ab + r * 128 + ((ks * 64 + g * 16) ^ swz));
        }
#pragma unroll
        for (int nf = 0; nf < NF; nf++) {
            int r = wn * (TN / 2) + nf * 16 + lq;
#pragma unroll
            for (int ks = 0; ks < 2; ks++)
                bfr[nf][ks] = *(const short8*)(Bb + r * 128 + ((ks * 64 + g * 16) ^ swz));
        }
        __builtin_amdgcn_s_setprio(1);
#pragma unroll
        for (int mf = 0; mf < MF; mf++)
#pragma unroll
            for (int nf = 0; nf < NF; nf++)
#pragma unroll
                for (int ks = 0; ks < 2; ks++)
                    acc[mf][nf] = __builtin_amdgcn_mfma_f32_16x16x32_bf16(
                        af[mf][ks], bfr[nf][ks], acc[mf][nf], 0, 0, 0);
        __builtin_amdgcn_s_setprio(0);
        asm volatile("s_waitcnt vmcnt(0)" ::: "memory");
        __builtin_amdgcn_s_barrier();
        cur ^= 1;
    }

#pragma unroll
    for (int mf = 0; mf < MF; mf++) {
#pragma unroll
        for (int nf = 0; nf < NF; nf++) {
            int ncol = n0 + wn * (TN / 2) + nf * 16 + lq;
            float bcol = bias[ncol];
#pragma unroll
            for (int j = 0; j < 4; j++) {
                int mrow = m0 + wm * (TM / 2) + mf * 16 + 4 * g + j;
                float v = acc[mf][nf][j] + bcol;
                v = 0.5f * v * (1.f + erff(v * 0.70710678118654752f));
                C[(size_t)mrow * N + ncol] = f2bu(v);
            }
        }
    }
}

// =========================== MFMA flash attention ===========================
// grid 512: xcd=bid&7 -> (h=(bid&7)>>1, outer=bid&1); qblk=bid>>3, 64 q/block.
// Block 512 thr = 8 waves = 2 q-chunks(32q) x 4 key-splits. Each split-stream:
// single-buffered K[32][128] (8KB, XOR-swz) + V row-pair-swz [96][128B] (12KB)
// -> 80KB total -> 2 blocks/CU -> 4 waves/SIMD. Wave = 32q (2 qg fragment
// groups sharing every LDS read). Per-lane deferred softmax; in-register P
// redistribution; in-block 3-phase merge of the 4 split partials.
__global__ __launch_bounds__(512, 4) void attn_mfma(
    const ushort_t* __restrict__ Qb,   // [4096][512] cols = h*128+d (pre-scaled)
    const ushort_t* __restrict__ Kb,   // [4096][512]
    const ushort_t* __restrict__ Vtb,  // [768][4096] rows = h*192+vd
    const int* __restrict__ batch_h, const int* __restrict__ batch_p,
    ushort_t* __restrict__ Opart,      // [2][4][4096][192]
    float* __restrict__ ml)            // [2][4][4096][2]
{
    const int bid = blockIdx.x;
    const int h = (bid & 7) >> 1;
    const int outer = bid & 1;
    const int n0 = (bid >> 3) * 64;    // 64 qblocks

    __shared__ __align__(16) char smem[81920];

    const int t = threadIdx.x;
    const int w = t >> 6;
    const int qc = w & 1;              // q-chunk (32 queries)
    const int si = w >> 1;             // key split 0..3
    const int lane = t & 63, lq = lane & 15, g = lane >> 4;
    const int lqm = (lq & 7) << 4;
    const bool hi = lane >= 32;
    const bool godd = (lane & 16) != 0;

    char* Kbuf = smem + si * 20480;         // [32][256B] swz
    char* Vbuf = Kbuf + 8192;               // [96][128B] row-pair swz

    // Q fragments: queries n0 + qc*32 + qg*16 + lq
    short8 qf[2][4];
    int bhq[2];
#pragma unroll
    for (int qg = 0; qg < 2; qg++) {
        const ushort_t* qrow = Qb + (size_t)(n0 + qc * 32 + qg * 16 + lq) * 512 + h * 128;
#pragma unroll
        for (int ks = 0; ks < 4; ks++)
            qf[qg][ks] = *(const short8*)(qrow + ks * 32 + g * 8);
        bhq[qg] = batch_h[n0 + qc * 32 + qg * 16 + lq];
    }
    const int bh_lo = batch_h[n0 + qc * 32];
    const int bh_hi = batch_h[n0 + qc * 32 + 31];

    f32x4 Ofr[2][12];
#pragma unroll
    for (int qg = 0; qg < 2; qg++)
#pragma unroll
        for (int nt = 0; nt < 12; nt++) Ofr[qg][nt] = (f32x4){0.f, 0.f, 0.f, 0.f};
    float m_run[2] = {-1e30f, -1e30f}, l_run[2] = {0.f, 0.f};

    const char* Kg = (const char*)Kb;
    const char* Vg = (const char*)Vtb;
    const int kb0 = (outer * 4 + si) * 512;

    // prefetch per-tile batch bounds (16 tiles of 32 keys)
    int tlo = 0, thi = 0;
    if (lane < 16) {
        tlo = batch_p[kb0 + lane * 32];
        thi = batch_p[kb0 + lane * 32 + 31];
    }
    // per-lane V read offset (row-pair swizzled)
    const int voff = ((lq >> 1) * 128) + ((((lq & 1) * 64) + g * 16) ^ (((lq >> 1) & 7) << 4));

    auto STAGE = [&](int m0k) {
        // K: 8 instrs per stream, 4 per wave
#pragma unroll
        for (int jj = 0; jj < 4; jj++) {
            int j = qc * 4 + jj;
            int r = j * 4 + (lane >> 4);
            int c = ((lane & 15) * 16) ^ ((r & 7) << 4);
            gl_lds16(Kg + (size_t)(m0k + r) * 1024 + h * 256 + c, Kbuf + j * 1024);
        }
        // V: 12 instrs per stream, 6 per wave (row-pair layout, inverse-swz src)
#pragma unroll
        for (int jj = 0; jj < 6; jj++) {
            int j = qc * 6 + jj;
            int r2 = j * 8 + (lane >> 3);
            int raw = ((lane & 7) * 16) ^ ((r2 & 7) << 4);
            int vd = 2 * r2 + (raw >> 6);
            int kbyt = raw & 63;
            gl_lds16(Vg + ((size_t)(h * 192 + vd) * 4096 + m0k) * 2 + kbyt, Vbuf + j * 1024);
        }
    };

    STAGE(kb0);
    asm volatile("s_waitcnt vmcnt(0)" ::: "memory");
    __builtin_amdgcn_s_barrier();

    for (int tile = 0; tile < 16; tile++) {
        const int ktb = kb0 + tile * 32;
        const int klo = __shfl(tlo, tile);
        const int khi = __shfl(thi, tile);
        const bool allmask = (klo == khi) && (klo == bh_lo) && (bh_lo == bh_hi);
        const bool needmask = (klo <= bh_hi) && (khi >= bh_lo);

        int4 bp0, bp1;
        if (needmask && !allmask) {
            bp0 = *(const int4*)&batch_p[ktb + 4 * g];
            bp1 = *(const int4*)&batch_p[ktb + 16 + 4 * g];
        }

        if (!allmask) {
            // ---- S^T = K·Q^T (both qg share every kf read) ----
            f32x4 S[2][2];
#pragma unroll
            for (int qg = 0; qg < 2; qg++)
#pragma unroll
                for (int mt = 0; mt < 2; mt++) S[qg][mt] = (f32x4){0.f, 0.f, 0.f, 0.f};
            __builtin_amdgcn_s_setprio(1);
#pragma unroll
            for (int mt = 0; mt < 2; mt++) {
                const char* rbase = Kbuf + (mt * 16 + lq) * 256;
#pragma unroll
                for (int ks = 0; ks < 4; ks++) {
                    short8 kf = *(const short8*)(rbase + ((ks * 64 + g * 16) ^ lqm));
                    S[0][mt] = __builtin_amdgcn_mfma_f32_16x16x32_bf16(kf, qf[0][ks], S[0][mt], 0, 0, 0);
                    S[1][mt] = __builtin_amdgcn_mfma_f32_16x16x32_bf16(kf, qf[1][ks], S[1][mt], 0, 0, 0);
                }
            }
            __builtin_amdgcn_s_setprio(0);

            // ---- mask + per-lane max ----
            float pmax[2];
#pragma unroll
            for (int qg = 0; qg < 2; qg++) {
                float m = -1e30f;
                if (needmask) {
                    float v0 = (bp0.x == bhq[qg]) ? -1e9f : S[qg][0][0];
                    float v1 = (bp0.y == bhq[qg]) ? -1e9f : S[qg][0][1];
                    float v2 = (bp0.z == bhq[qg]) ? -1e9f : S[qg][0][2];
                    float v3 = (bp0.w == bhq[qg]) ? -1e9f : S[qg][0][3];
                    S[qg][0][0] = v0; S[qg][0][1] = v1; S[qg][0][2] = v2; S[qg][0][3] = v3;
                    float u0 = (bp1.x == bhq[qg]) ? -1e9f : S[qg][1][0];
                    float u1 = (bp1.y == bhq[qg]) ? -1e9f : S[qg][1][1];
                    float u2 = (bp1.z == bhq[qg]) ? -1e9f : S[qg][1][2];
                    float u3 = (bp1.w == bhq[qg]) ? -1e9f : S[qg][1][3];
                    S[qg][1][0] = u0; S[qg][1][1] = u1; S[qg][1][2] = u2; S[qg][1][3] = u3;
                    m = fmaxf(fmaxf(fmaxf(v0, v1), fmaxf(v2, v3)),
                              fmaxf(fmaxf(u0, u1), fmaxf(u2, u3)));
                } else {
#pragma unroll
                    for (int mt = 0; mt < 2; mt++)
                        m = fmaxf(m, fmaxf(fmaxf(S[qg][mt][0], S[qg][mt][1]),
                                           fmaxf(S[qg][mt][2], S[qg][mt][3])));
                }
                pmax[qg] = m;
            }
            bool ng = __all((pmax[0] <= m_run[0] + 8.f) && (pmax[1] <= m_run[1] + 8.f));
            if (!ng) {
#pragma unroll
                for (int qg = 0; qg < 2; qg++) {
                    float mq = fmaxf(pmax[qg], m_run[qg]);
                    mq = fmaxf(mq, __shfl_xor(mq, 16));
                    mq = fmaxf(mq, __shfl_xor(mq, 32));
                    float f = exp2f(m_run[qg] - mq);
                    m_run[qg] = mq;
                    l_run[qg] *= f;
                    float fr0 = __shfl(f, 4 * g + 0);
                    float fr1 = __shfl(f, 4 * g + 1);
                    float fr2 = __shfl(f, 4 * g + 2);
                    float fr3 = __shfl(f, 4 * g + 3);
#pragma unroll
                    for (int nt = 0; nt < 12; nt++) {
                        Ofr[qg][nt][0] *= fr0; Ofr[qg][nt][1] *= fr1;
                        Ofr[qg][nt][2] *= fr2; Ofr[qg][nt][3] *= fr3;
                    }
                }
            }

            // ---- exp2 + per-lane partial l + pack P ----
            uint2 P2[2][2];
#pragma unroll
            for (int qg = 0; qg < 2; qg++) {
                float lsum = 0.f;
#pragma unroll
                for (int mt = 0; mt < 2; mt++) {
                    float e0 = exp2f(S[qg][mt][0] - m_run[qg]);
                    float e1 = exp2f(S[qg][mt][1] - m_run[qg]);
                    float e2 = exp2f(S[qg][mt][2] - m_run[qg]);
                    float e3 = exp2f(S[qg][mt][3] - m_run[qg]);
                    lsum += (e0 + e1) + (e2 + e3);
                    P2[qg][mt].x = pkbf(e0, e1);
                    P2[qg][mt].y = pkbf(e2, e3);
                }
                l_run[qg] += lsum;
            }

            // ---- O += P·V (single K=32 step; both qg share vf reads) ----
            short8 pf0 = mkfrag(P2[0][0], P2[0][1], hi, godd);
            short8 pf1 = mkfrag(P2[1][0], P2[1][1], hi, godd);
            __builtin_amdgcn_s_setprio(1);
#pragma unroll
            for (int nt = 0; nt < 12; nt++) {
                short8 vf = *(const short8*)(Vbuf + nt * 1024 + voff);
                Ofr[0][nt] = __builtin_amdgcn_mfma_f32_16x16x32_bf16(pf0, vf, Ofr[0][nt], 0, 0, 0);
                Ofr[1][nt] = __builtin_amdgcn_mfma_f32_16x16x32_bf16(pf1, vf, Ofr[1][nt], 0, 0, 0);
            }
            __builtin_amdgcn_s_setprio(0);
        }

        __builtin_amdgcn_s_barrier();            // all streams done reading bufs
        if (tile + 1 < 16) STAGE(ktb + 32);
        asm volatile("s_waitcnt vmcnt(0)" ::: "memory");
        __builtin_amdgcn_s_barrier();            // staged data visible
    }

    // ---- reduce per-lane l partials ----
    float lt[2];
#pragma unroll
    for (int qg = 0; qg < 2; qg++) {
        float l = l_run[qg];
        l += __shfl_xor(l, 16);
        l += __shfl_xor(l, 32);
        lt[qg] = l;
    }

    // ---- 3-phase in-block merge of the 4 split partials into si==0 ----
    float* mO = (float*)smem;                     // [2 qc][64 lane][96]
    float* mls = (float*)(smem + 49152);          // [2 qc][2 qg][16 lq][2]
    float m_acc[2] = {m_run[0], m_run[1]};
    float l_acc[2] = {lt[0], lt[1]};

    for (int p = 1; p < 4; p++) {
        __syncthreads();
        if (si == p) {
            float* dst = mO + ((size_t)qc * 64 + lane) * 96;
#pragma unroll
            for (int qg = 0; qg < 2; qg++) {
#pragma unroll
                for (int nt = 0; nt < 12; nt++)
                    *(f32x4*)(dst + qg * 48 + nt * 4) = Ofr[qg][nt];
                if (g == 0) {
                    mls[(((qc * 2 + qg) * 16) + lq) * 2 + 0] = m_run[qg];
                    mls[(((qc * 2 + qg) * 16) + lq) * 2 + 1] = lt[qg];
                }
            }
        }
        __syncthreads();
        if (si == 0) {
            const float* srcO = mO + ((size_t)qc * 64 + lane) * 96;
#pragma unroll
            for (int qg = 0; qg < 2; qg++) {
                float m1 = mls[(((qc * 2 + qg) * 16) + lq) * 2 + 0];
                float l1 = mls[(((qc * 2 + qg) * 16) + lq) * 2 + 1];
                float m = fmaxf(m_acc[qg], m1);
                float a0 = exp2f(m_acc[qg] - m), a1 = exp2f(m1 - m);
                l_acc[qg] = l_acc[qg] * a0 + l1 * a1;
                m_acc[qg] = m;
                float f0[4], f1[4];
#pragma unroll
                for (int j = 0; j < 4; j++) {
                    f0[j] = __shfl(a0, 4 * g + j);
                    f1[j] = __shfl(a1, 4 * g + j);
                }
#pragma unroll
                for (int nt = 0; nt < 12; nt++) {
                    f32x4 o1 = *(const f32x4*)(srcO + qg * 48 + nt * 4);
#pragma unroll
                    for (int j = 0; j < 4; j++)
                        Ofr[qg][nt][j] = Ofr[qg][nt][j] * f0[j] + o1[j] * f1[j];
                }
            }
        }
    }

    if (si == 0) {
        const size_t plane = (size_t)(outer * 4 + h) * 4096;
#pragma unroll
        for (int qg = 0; qg < 2; qg++) {
            int q0 = n0 + qc * 32 + qg * 16;
            if (g == 0) {
                ml[(plane + q0 + lq) * 2 + 0] = m_acc[qg];
                ml[(plane + q0 + lq) * 2 + 1] = l_acc[qg];
            }
#pragma unroll
            for (int nt = 0; nt < 12; nt++)
#pragma unroll
                for (int j = 0; j < 4; j++)
                    Opart[(plane + q0 + 4 * g + j) * 192 + nt * 16 + lq] = f2bu(Ofr[qg][nt][j]);
        }
    }
}

// ============== combine outer key-split + build feats tail ==============
__global__ __launch_bounds__(256) void combine_feats(
    const ushort_t* __restrict__ Opart, const float* __restrict__ ml,
    const float* __restrict__ lhs_h, ushort_t* __restrict__ feats)
{
    const int t = threadIdx.x;
#pragma unroll
    for (int i = 0; i < 4; i++) {
        int q = blockIdx.x * 4 + i;
#pragma unroll
        for (int it = 0; it < 3; it++) {
            int c = t + it * 256;
            int h = c / 192, vd = c - h * 192;
            size_t i0 = (size_t)h * 4096 + q;
            size_t i1 = (size_t)(4 + h) * 4096 + q;
            float m0 = ml[i0 * 2], l0 = ml[i0 * 2 + 1];
            float m1 = ml[i1 * 2], l1 = ml[i1 * 2 + 1];
            float m = fmaxf(m0, m1);
            float e0 = exp2f(m0 - m), e1 = exp2f(m1 - m);
            float linv = 1.f / (l0 * e0 + l1 * e1);
            float O = (b2f(Opart[i0 * 192 + vd]) * e0 + b2f(Opart[i1 * 192 + vd]) * e1) * linv;
            feats[(size_t)q * 1280 + 512 + c] = f2bu(lhs_h[(size_t)q * 768 + c] - O);
        }
    }
}

// ================= h2 = h1 @ W2 (f32) + LayerNorm(128) ======================
__global__ __launch_bounds__(256) void h2_ln(
    const ushort_t* __restrict__ h1, const float* __restrict__ W2,
    const float* __restrict__ ln_g, const float* __restrict__ ln_b,
    float* __restrict__ h2out)
{
    const int n0 = blockIdx.x * 8;
    const int t = threadIdx.x;
    __shared__ float h1s[8][256];
    __shared__ float h2s[8][128];

#pragma unroll
    for (int i = 0; i < 8; i++) {
        int idx = t + i * 256; int r = idx >> 8, c = idx & 255;
        h1s[r][c] = b2f(h1[(size_t)(n0 + r) * 256 + c]);
    }
    __syncthreads();

    {
        int o2 = t & 127, gq = t >> 7;
        float acc[4] = {};
        for (int k4 = 0; k4 < 64; k4++) {
            float w0 = W2[(size_t)(k4 * 4 + 0) * 128 + o2];
            float w1 = W2[(size_t)(k4 * 4 + 1) * 128 + o2];
            float w2 = W2[(size_t)(k4 * 4 + 2) * 128 + o2];
            float w3 = W2[(size_t)(k4 * 4 + 3) * 128 + o2];
#pragma unroll
            for (int q = 0; q < 4; q++) {
                float4 hh = *(const float4*)&h1s[gq * 4 + q][k4 * 4];
                acc[q] += hh.x * w0 + hh.y * w1 + hh.z * w2 + hh.w * w3;
            }
        }
#pragma unroll
        for (int q = 0; q < 4; q++) h2s[gq * 4 + q][o2] = acc[q];
    }
    __syncthreads();

    {
        int wv = t >> 6, lane = t & 63;
#pragma unroll
        for (int sx = 0; sx < 2; sx++) {
            int nd = wv * 2 + sx;
            float x0 = h2s[nd][lane], x1 = h2s[nd][lane + 64];
            float sum = x0 + x1;
#pragma unroll
            for (int off = 32; off; off >>= 1) sum += __shfl_xor(sum, off);
            float mu = sum * (1.f / 128.f);
            float d0 = x0 - mu, d1 = x1 - mu;
            float s2 = d0 * d0 + d1 * d1;
#pragma unroll
            for (int off = 32; off; off >>= 1) s2 += __shfl_xor(s2, off);
            float rstd = rsqrtf(s2 * (1.f / 128.f) + 1e-5f);
            size_t base = (size_t)(n0 + nd) * 128;
            h2out[base + lane]      = d0 * rstd * ln_g[lane] + ln_b[lane];
            h2out[base + lane + 64] = d1 * rstd * ln_g[lane + 64] + ln_b[lane + 64];
        }
    }
}

// ============ pool (mean per graph, binary-search ranges) + classifier ======
__global__ __launch_bounds__(128) void pool_cls(
    const float* __restrict__ h2, const int* __restrict__ batch_h,
    const float* __restrict__ Wc, const float* __restrict__ bc,
    float* __restrict__ out)
{
    int b = blockIdx.x, t = threadIdx.x;
    __shared__ int bounds[2];
    if (t < 2) {
        int target = b + t;
        int lo = 0, hi = NH_N;
        while (lo < hi) {
            int mid = (lo + hi) >> 1;
            if (batch_h[mid] < target) lo = mid + 1; else hi = mid;
        }
        bounds[t] = lo;
    }
    __syncthreads();
    int s = bounds[0], e = bounds[1];
    float acc = 0.f;
    for (int n = s; n < e; n++) acc += h2[(size_t)n * 128 + t];
    float pooled = acc / fmaxf((float)(e - s), 1.f);
    __shared__ float red[128];
    for (int c = 0; c < 3; c++) {
        red[t] = pooled * Wc[t * 3 + c];
        __syncthreads();
        for (int off = 64; off > 0; off >>= 1) {
            if (t < off) red[t] += red[t + off];
            __syncthreads();
        }
        if (t == 0) out[b * 3 + c] = red[0] + bc[c];
        __syncthreads();
    }
}

// ---------------------------------------------------------------------------
extern "C" void kernel_launch(void* const* d_in, const int* in_sizes, int n_in,
                              void* d_out, int out_size, void* d_ws, size_t ws_size,
                              hipStream_t stream)
{
    const float* ctx_p  = (const float*)d_in[0];
    const float* ctx_h  = (const float*)d_in[1];
    const float* lhs_p  = (const float*)d_in[2];
    const float* lhs_h  = (const float*)d_in[3];
    const int*   batch_p = (const int*)d_in[4];
    const int*   batch_h = (const int*)d_in[5];
    const float* Wq = (const float*)d_in[6];
    const float* bq = (const float*)d_in[7];
    const float* Wk = (const float*)d_in[8];
    const float* bk = (const float*)d_in[9];
    const float* Wv = (const float*)d_in[10];
    const float* bv = (const float*)d_in[11];
    const float* W1 = (const float*)d_in[12];
    const float* b1 = (const float*)d_in[13];
    const float* W2 = (const float*)d_in[14];
    const float* ln_g = (const float*)d_in[15];
    const float* ln_b = (const float*)d_in[16];
    const float* Wc = (const float*)d_in[17];
    const float* bc = (const float*)d_in[18];
    float* out = (float*)d_out;

    // ---- workspace layout (ushort units unless noted) ----
    ushort_t* u = (ushort_t*)d_ws;
    ushort_t* ctxp_bf = u;                         // 2097152
    ushort_t* lhsp_bf = ctxp_bf + 2097152;         // 3145728
    ushort_t* Wqt  = lhsp_bf + 3145728;            // 262144
    ushort_t* Wkt  = Wqt + 262144;                 // 262144
    ushort_t* Wvt  = Wkt + 262144;                 // 589824
    ushort_t* Opart = u;                           // ALIAS: 6291456 over [ctxp..Wvt]
    ushort_t* W1t  = Wvt + 589824;                 // 327680
    ushort_t* Qb   = W1t + 327680;                 // 2097152
    ushort_t* Kb   = Qb + 2097152;                 // 2097152
    ushort_t* Vtb  = Kb + 2097152;                 // 3145728
    ushort_t* feats = Vtb + 3145728;               // 5242880
    ushort_t* h1   = feats + 5242880;              // 1048576
    float* ml  = (float*)(h1 + 1048576);           // 65536 f32
    float* h2  = ml + 65536;                       // 524288 f32
    float* bqp = h2 + 524288;                      // 512
    float* bkp = bqp + 512;                        // 512

    convert_all<<<864, 256, 0, stream>>>(
        ctx_h, ctx_p, lhs_p, Wq, Wk, Wv, W1, bq, bk,
        ctxp_bf, lhsp_bf, feats, Wqt, Wkt, Wvt, W1t, bqp, bkp);

    gemm_qkv<<<896, 256, 0, stream>>>(
        feats, ctxp_bf, Wqt, Wkt, Wvt, lhsp_bf, bqp, bkp, bv, Qb, Kb, Vtb);

    attn_mfma<<<512, 512, 0, stream>>>(Qb, Kb, Vtb, batch_h, batch_p, Opart, ml);

    combine_feats<<<1024, 256, 0, stream>>>(Opart, ml, lhs_h, feats);

    gemm_mlp1<64, 64><<<dim3(4, 64), 256, 0, stream>>>(feats, 1280, W1t, b1, h1, NH_N, 256, 1280);

    h2_ln<<<512, 256, 0, stream>>>(h1, W2, ln_g, ln_b, h2);
    pool_cls<<<B_N, 128, 0, stream>>>(h2, batch_h, Wc, bc, out);
}

// Round 9
// 193.229 us; speedup vs baseline: 3.2141x; 3.2141x over previous
//
#include <hip/hip_runtime.h>
#include <hip/hip_bf16.h>
#include <math.h>

#define NP_N 4096
#define NH_N 4096
#define D_N 512
#define BERT_N 768
#define H_N 4
#define B_N 32
#define SCL2 0.12754245006257576f   // log2(e)/sqrt(128), folded into Wq/bq

typedef __attribute__((ext_vector_type(8))) short short8;
typedef __attribute__((ext_vector_type(4))) float f32x4;
typedef __attribute__((ext_vector_type(4))) unsigned short ush4;
typedef __attribute__((ext_vector_type(4))) unsigned int uivec4;
typedef unsigned short ushort_t;

__device__ __forceinline__ void gl_lds16(const void* g, void* l) {
    __builtin_amdgcn_global_load_lds((const __attribute__((address_space(1))) void*)g,
                                     (__attribute__((address_space(3))) void*)l, 16, 0, 0);
}
__device__ __forceinline__ unsigned short f2bu(float f) {
    __hip_bfloat16 b = __float2bfloat16(f);
    return *reinterpret_cast<unsigned short*>(&b);
}
__device__ __forceinline__ float b2f(unsigned short u) {
    union { unsigned int i; float f; } x; x.i = ((unsigned int)u) << 16; return x.f;
}
__device__ __forceinline__ unsigned int pkbf(float a, float b) {
    union { __hip_bfloat162 h; unsigned int u; } x;
    x.h.x = __float2bfloat16(a);
    x.h.y = __float2bfloat16(b);
    return x.u;
}
__device__ __forceinline__ unsigned int sxor(unsigned int v, int m) {
    return (unsigned int)__shfl_xor((int)v, m);
}

// Build PV A-fragment from QK^T C-layout pairs (verified rounds 3-6).
__device__ __forceinline__ short8 mkfrag(uint2 u, uint2 v, bool hi, bool godd) {
    unsigned ux32 = sxor(u.x, 32), uy32 = sxor(u.y, 32);
    unsigned vx32 = sxor(v.x, 32), vy32 = sxor(v.y, 32);
    unsigned ax = hi ? vx32 : u.x, bx = hi ? v.x : ux32;
    unsigned ay = hi ? vy32 : u.y, by = hi ? v.y : uy32;
    unsigned sbx = sxor(bx, 16), sax = sxor(ax, 16);
    unsigned sby = sxor(by, 16), say = sxor(ay, 16);
    uivec4 w;
    w.x = godd ? sbx : ax;
    w.y = godd ? sby : ay;
    w.z = godd ? bx : sax;
    w.w = godd ? by : say;
    return __builtin_bit_cast(short8, w);
}

// =========================== convert + transpose ===========================
// blocks [0,128): ctx_h -> feats[:, :512] bf16
// blocks [128,256): ctx_p -> ctxp_bf
// blocks [256,448): lhs_p -> lhsp_bf
// blocks [448,800): 64x64 weight transposes (Wq perm+scl, Wk perm, Wv, W1)
__global__ __launch_bounds__(256) void convert_all(
    const float* __restrict__ ctx_h, const float* __restrict__ ctx_p,
    const float* __restrict__ lhs_p,
    const float* __restrict__ Wq, const float* __restrict__ Wk,
    const float* __restrict__ Wv, const float* __restrict__ W1,
    const float* __restrict__ bq, const float* __restrict__ bk,
    ushort_t* __restrict__ ctxp_bf, ushort_t* __restrict__ lhsp_bf,
    ushort_t* __restrict__ feats,
    ushort_t* __restrict__ Wqt, ushort_t* __restrict__ Wkt,
    ushort_t* __restrict__ Wvt, ushort_t* __restrict__ W1t,
    float* __restrict__ bqp, float* __restrict__ bkp)
{
    const int bid = blockIdx.x, t = threadIdx.x;
    if (bid < 128) {
        // ctx_h 524288 float4 -> feats rows (stride 320 ush4)
        for (long k = (long)bid * 256 + t; k < 524288; k += 128 * 256) {
            float4 v = ((const float4*)ctx_h)[k];
            ush4 o; o[0] = f2bu(v.x); o[1] = f2bu(v.y); o[2] = f2bu(v.z); o[3] = f2bu(v.w);
            long n = k >> 7, c4 = k & 127;
            ((ush4*)feats)[n * 320 + c4] = o;
        }
        if (bid == 0) {
            for (int n = t; n < 512; n += 256) {
                int np = (n & 3) * 128 + (n >> 2);
                bqp[np] = bq[n] * SCL2;
                bkp[np] = bk[n];
            }
        }
        return;
    }
    if (bid < 256) {
        for (long k = (long)(bid - 128) * 256 + t; k < 524288; k += 128 * 256) {
            float4 v = ((const float4*)ctx_p)[k];
            ush4 o; o[0] = f2bu(v.x); o[1] = f2bu(v.y); o[2] = f2bu(v.z); o[3] = f2bu(v.w);
            ((ush4*)ctxp_bf)[k] = o;
        }
        return;
    }
    if (bid < 448) {
        for (long k = (long)(bid - 256) * 256 + t; k < 786432; k += 192 * 256) {
            float4 v = ((const float4*)lhs_p)[k];
            ush4 o; o[0] = f2bu(v.x); o[1] = f2bu(v.y); o[2] = f2bu(v.z); o[3] = f2bu(v.w);
            ((ush4*)lhsp_bf)[k] = o;
        }
        return;
    }
    // weight transposes
    int tb = bid - 448;
    const float* src; ushort_t* dst; int K, N, tile, perm; float wscl;
    if (tb < 64)       { src = Wq; dst = Wqt; K = 512;  N = 512; tile = tb;       perm = 1; wscl = SCL2; }
    else if (tb < 128) { src = Wk; dst = Wkt; K = 512;  N = 512; tile = tb - 64;  perm = 1; wscl = 1.f; }
    else if (tb < 272) { src = Wv; dst = Wvt; K = 768;  N = 768; tile = tb - 128; perm = 0; wscl = 1.f; }
    else               { src = W1; dst = W1t; K = 1280; N = 256; tile = tb - 272; perm = 0; wscl = 1.f; }
    int ntn = N >> 6;
    int k0 = (tile / ntn) * 64, n0 = (tile % ntn) * 64;
    __shared__ float tl[64][65];
#pragma unroll
    for (int i = 0; i < 16; i++) {
        int idx = t + i * 256; int r = idx >> 6, c = idx & 63;
        tl[r][c] = src[(size_t)(k0 + r) * N + n0 + c];
    }
    __syncthreads();
#pragma unroll
    for (int i = 0; i < 16; i++) {
        int idx = t + i * 256; int r = idx >> 6, c = idx & 63;
        int n = n0 + r;
        int nr = perm ? ((n & 3) * 128 + (n >> 2)) : n;
        dst[(size_t)nr * K + k0 + c] = f2bu(tl[c][r] * wscl);
    }
}

// ============ fused Q/K/V projection GEMMs (64x64 tiles, one launch) ========
__global__ __launch_bounds__(256) void gemm_qkv(
    const ushort_t* __restrict__ feats, const ushort_t* __restrict__ ctxp,
    const ushort_t* __restrict__ Wqt, const ushort_t* __restrict__ Wkt,
    const ushort_t* __restrict__ Wvt, const ushort_t* __restrict__ lhsp,
    const float* __restrict__ bqp, const float* __restrict__ bkp,
    const float* __restrict__ bv,
    ushort_t* __restrict__ Qb, ushort_t* __restrict__ Kb,
    ushort_t* __restrict__ Vtb)
{
    int b = blockIdx.x;
    const ushort_t *A, *Bt; const float* bias; ushort_t* C;
    int lda, N, K, m0, n0, bias_row;
    if (b < 512) {            // Q: M=4096, N=512, K=512 (A = feats[:, :512])
        A = feats; lda = 1280; Bt = Wqt; bias = bqp; C = Qb;
        N = 512; K = 512; bias_row = 0;
        n0 = (b & 7) * 64; m0 = (b >> 3) * 64;
    } else if (b < 1024) {    // K
        b -= 512;
        A = ctxp; lda = 512; Bt = Wkt; bias = bkp; C = Kb;
        N = 512; K = 512; bias_row = 0;
        n0 = (b & 7) * 64; m0 = (b >> 3) * 64;
    } else {                  // V^T: M=768 (Wvt rows), N=4096, K=768
        b -= 1024;
        A = Wvt; lda = 768; Bt = lhsp; bias = bv; C = Vtb;
        N = 4096; K = 768; bias_row = 1;
        n0 = (b & 63) * 64; m0 = (b >> 6) * 64;
    }
    const int nsteps = K >> 6;

    __shared__ ushort_t As[2][64 * 64];
    __shared__ ushort_t Bs[2][64 * 64];
    const int t = threadIdx.x, w = t >> 6, lane = t & 63;
    const int lq = lane & 15, g = lane >> 4;
    const int wm = w >> 1, wn = w & 1;

    f32x4 acc[2][2] = {};

    auto STAGE = [&](int buf, int k0) {
#pragma unroll
        for (int jj = 0; jj < 2; jj++) {
            int j = w * 2 + jj;
            int r = j * 8 + (lane >> 3);
            int c = (lane & 7) * 16;
            int cs = c ^ ((r & 7) << 4);
            gl_lds16((const char*)A + ((size_t)(m0 + r) * lda + k0) * 2 + cs,
                     (void*)&As[buf][j * 512]);
            gl_lds16((const char*)Bt + ((size_t)(n0 + r) * K + k0) * 2 + cs,
                     (void*)&Bs[buf][j * 512]);
        }
    };

    STAGE(0, 0);
    __syncthreads();
    int cur = 0;
    for (int s = 0; s < nsteps; s++) {
        if (s + 1 < nsteps) STAGE(cur ^ 1, (s + 1) * 64);
        const char* Ab = (const char*)&As[cur][0];
        const char* Bb = (const char*)&Bs[cur][0];
        const int swz = (lq & 7) << 4;
        short8 af[2][2], bfr[2][2];
#pragma unroll
        for (int mf = 0; mf < 2; mf++) {
            int r = wm * 32 + mf * 16 + lq;
#pragma unroll
            for (int ks = 0; ks < 2; ks++)
                af[mf][ks] = *(const short8*)(Ab + r * 128 + ((ks * 64 + g * 16) ^ swz));
        }
#pragma unroll
        for (int nf = 0; nf < 2; nf++) {
            int r = wn * 32 + nf * 16 + lq;
#pragma unroll
            for (int ks = 0; ks < 2; ks++)
                bfr[nf][ks] = *(const short8*)(Bb + r * 128 + ((ks * 64 + g * 16) ^ swz));
        }
#pragma unroll
        for (int mf = 0; mf < 2; mf++)
#pragma unroll
            for (int nf = 0; nf < 2; nf++)
#pragma unroll
                for (int ks = 0; ks < 2; ks++)
                    acc[mf][nf] = __builtin_amdgcn_mfma_f32_16x16x32_bf16(
                        af[mf][ks], bfr[nf][ks], acc[mf][nf], 0, 0, 0);
        __syncthreads();
        cur ^= 1;
    }

#pragma unroll
    for (int mf = 0; mf < 2; mf++) {
#pragma unroll
        for (int nf = 0; nf < 2; nf++) {
            int ncol = n0 + wn * 32 + nf * 16 + lq;
            float bcol = bias_row ? 0.f : bias[ncol];
#pragma unroll
            for (int j = 0; j < 4; j++) {
                int mrow = m0 + wm * 32 + mf * 16 + 4 * g + j;
                float v = acc[mf][nf][j] + (bias_row ? bias[mrow] : bcol);
                C[(size_t)mrow * N + ncol] = f2bu(v);
            }
        }
    }
}

// ======================= MLP1 GEMM (64x64, GELU) ============================
__global__ __launch_bounds__(256) void gemm_mlp1(
    const ushort_t* __restrict__ A, int lda, const ushort_t* __restrict__ Bt,
    const float* __restrict__ bias, ushort_t* __restrict__ C,
    int M, int N, int K)
{
    __shared__ ushort_t As[2][64 * 64];
    __shared__ ushort_t Bs[2][64 * 64];
    const int t = threadIdx.x, w = t >> 6, lane = t & 63;
    const int lq = lane & 15, g = lane >> 4;
    const int wm = w >> 1, wn = w & 1;
    const int n0 = blockIdx.x * 64, m0 = blockIdx.y * 64;
    const int nsteps = K >> 6;

    f32x4 acc[2][2] = {};

    auto STAGE = [&](int buf, int k0) {
#pragma unroll
        for (int jj = 0; jj < 2; jj++) {
            int j = w * 2 + jj;
            int r = j * 8 + (lane >> 3);
            int c = (lane & 7) * 16;
            int cs = c ^ ((r & 7) << 4);
            gl_lds16((const char*)A + ((size_t)(m0 + r) * lda + k0) * 2 + cs,
                     (void*)&As[buf][j * 512]);
            gl_lds16((const char*)Bt + ((size_t)(n0 + r) * K + k0) * 2 + cs,
                     (void*)&Bs[buf][j * 512]);
        }
    };

    STAGE(0, 0);
    __syncthreads();
    int cur = 0;
    for (int s = 0; s < nsteps; s++) {
        if (s + 1 < nsteps) STAGE(cur ^ 1, (s + 1) * 64);
        const char* Ab = (const char*)&As[cur][0];
        const char* Bb = (const char*)&Bs[cur][0];
        const int swz = (lq & 7) << 4;
        short8 af[2][2], bfr[2][2];
#pragma unroll
        for (int mf = 0; mf < 2; mf++) {
            int r = wm * 32 + mf * 16 + lq;
#pragma unroll
            for (int ks = 0; ks < 2; ks++)
                af[mf][ks] = *(const short8*)(Ab + r * 128 + ((ks * 64 + g * 16) ^ swz));
        }
#pragma unroll
        for (int nf = 0; nf < 2; nf++) {
            int r = wn * 32 + nf * 16 + lq;
#pragma unroll
            for (int ks = 0; ks < 2; ks++)
                bfr[nf][ks] = *(const short8*)(Bb + r * 128 + ((ks * 64 + g * 16) ^ swz));
        }
#pragma unroll
        for (int mf = 0; mf < 2; mf++)
#pragma unroll
            for (int nf = 0; nf < 2; nf++)
#pragma unroll
                for (int ks = 0; ks < 2; ks++)
                    acc[mf][nf] = __builtin_amdgcn_mfma_f32_16x16x32_bf16(
                        af[mf][ks], bfr[nf][ks], acc[mf][nf], 0, 0, 0);
        __syncthreads();
        cur ^= 1;
    }

#pragma unroll
    for (int mf = 0; mf < 2; mf++) {
#pragma unroll
        for (int nf = 0; nf < 2; nf++) {
            int ncol = n0 + wn * 32 + nf * 16 + lq;
            float bcol = bias[ncol];
#pragma unroll
            for (int j = 0; j < 4; j++) {
                int mrow = m0 + wm * 32 + mf * 16 + 4 * g + j;
                float v = acc[mf][nf][j] + bcol;
                v = 0.5f * v * (1.f + erff(v * 0.70710678118654752f));
                C[(size_t)mrow * N + ncol] = f2bu(v);
            }
        }
    }
}

// =========================== MFMA flash attention ===========================
// Round-6 structure verbatim (measured 85.4 us): grid 256, 8 waves, quads own
// independent 1024-key streams with private dbuf K/V LDS (160KB). Wave = 32q
// (2 fragment groups sharing every LDS read). Per-lane deferred softmax;
// in-register P redistribution; ONE barrier + ONE vmcnt drain per tile.
__global__ __launch_bounds__(512, 2) void attn_mfma(
    const ushort_t* __restrict__ Qb,   // [4096][512] cols = h*128+d (pre-scaled)
    const ushort_t* __restrict__ Kb,   // [4096][512]
    const ushort_t* __restrict__ Vtb,  // [768][4096] rows = h*192+vd
    const int* __restrict__ batch_h, const int* __restrict__ batch_p,
    ushort_t* __restrict__ Opart,      // [2][4][4096][192]
    float* __restrict__ ml)            // [2][4][4096][2]
{
    const int bid = blockIdx.x;
    const int h = (bid & 7) >> 1;
    const int s = bid & 1;
    const int n0 = (bid >> 3) * 128;

    __shared__ __align__(16) char smem[163840];

    const int t = threadIdx.x;
    const int w = t >> 6, o = w >> 2, wq = w & 3;
    const int lane = t & 63, lq = lane & 15, g = lane >> 4;
    const int lqm = (lq & 7) << 4;
    const bool hi = lane >= 32;
    const bool godd = (lane & 16) != 0;

    char* Kt0 = smem + (o * 2 + 0) * 16384;          // [64][128] bf16
    char* Kt1 = smem + (o * 2 + 1) * 16384;
    char* Vt0 = smem + 65536 + (o * 2 + 0) * 24576;  // [192][64] bf16
    char* Vt1 = smem + 65536 + (o * 2 + 1) * 24576;

    short8 qf[2][4];
    int bhq[2];
#pragma unroll
    for (int qg = 0; qg < 2; qg++) {
        const ushort_t* qrow = Qb + (size_t)(n0 + wq * 32 + qg * 16 + lq) * 512 + h * 128;
#pragma unroll
        for (int ks = 0; ks < 4; ks++)
            qf[qg][ks] = *(const short8*)(qrow + ks * 32 + g * 8);
        bhq[qg] = batch_h[n0 + wq * 32 + qg * 16 + lq];
    }

    f32x4 Ofr[2][12];
#pragma unroll
    for (int qg = 0; qg < 2; qg++)
#pragma unroll
        for (int nt = 0; nt < 12; nt++) Ofr[qg][nt] = (f32x4){0.f, 0.f, 0.f, 0.f};
    float m_run[2] = {-1e30f, -1e30f}, l_run[2] = {0.f, 0.f};

    const char* Kg = (const char*)Kb;
    const char* Vg = (const char*)Vtb;
    const int kb = s * 2048 + o * 1024;

    auto STAGE = [&](char* Kd, char* Vd, int m0k) {
#pragma unroll
        for (int jj = 0; jj < 4; jj++) {              // K: 16 instrs / quad
            int j = wq * 4 + jj;
            int r = j * 4 + (lane >> 4);
            int c = (lane & 15) * 16;
            gl_lds16(Kg + (size_t)(m0k + r) * 1024 + h * 256 + (c ^ ((r & 7) << 4)),
                     Kd + j * 1024);
        }
#pragma unroll
        for (int jj = 0; jj < 6; jj++) {              // V: 24 instrs / quad
            int j = wq * 6 + jj;
            int r = j * 8 + (lane >> 3);
            int c = (lane & 7) * 16;
            gl_lds16(Vg + ((size_t)(h * 192 + r) * 4096 + m0k) * 2 + (c ^ ((r & 7) << 4)),
                     Vd + j * 1024);
        }
    };

    STAGE(Kt0, Vt0, kb);
    asm volatile("s_waitcnt vmcnt(0)" ::: "memory");
    __builtin_amdgcn_s_barrier();
    int cur = 0;

    for (int tile = 0; tile < 16; tile++) {
        char* Kc = cur ? Kt1 : Kt0;
        char* Vc = cur ? Vt1 : Vt0;
        const int ktb = kb + tile * 64;

        // mask ids first (so their waitcnt doesn't force the stage to drain)
        int4 bp4[4];
#pragma unroll
        for (int mt = 0; mt < 4; mt++)
            bp4[mt] = *(const int4*)&batch_p[ktb + mt * 16 + 4 * g];

        if (tile + 1 < 16) STAGE(cur ? Kt0 : Kt1, cur ? Vt0 : Vt1, kb + (tile + 1) * 64);

        // ---- S^T = K·Q^T (pre-scaled) ----
        f32x4 S[2][4];
#pragma unroll
        for (int qg = 0; qg < 2; qg++)
#pragma unroll
            for (int mt = 0; mt < 4; mt++) S[qg][mt] = (f32x4){0.f, 0.f, 0.f, 0.f};
        __builtin_amdgcn_s_setprio(1);
#pragma unroll
        for (int mt = 0; mt < 4; mt++) {
            const char* rbase = Kc + (mt * 16 + lq) * 256;
#pragma unroll
            for (int ks = 0; ks < 4; ks++) {
                short8 kf = *(const short8*)(rbase + ((ks * 64 + g * 16) ^ lqm));
                S[0][mt] = __builtin_amdgcn_mfma_f32_16x16x32_bf16(kf, qf[0][ks], S[0][mt], 0, 0, 0);
                S[1][mt] = __builtin_amdgcn_mfma_f32_16x16x32_bf16(kf, qf[1][ks], S[1][mt], 0, 0, 0);
            }
        }
        __builtin_amdgcn_s_setprio(0);

        // ---- mask + per-lane max (no cross-lane in common path) ----
        float pmax[2];
#pragma unroll
        for (int qg = 0; qg < 2; qg++) {
            float m = -1e30f;
#pragma unroll
            for (int mt = 0; mt < 4; mt++) {
                float v0 = (bp4[mt].x == bhq[qg]) ? -1e9f : S[qg][mt][0];
                float v1 = (bp4[mt].y == bhq[qg]) ? -1e9f : S[qg][mt][1];
                float v2 = (bp4[mt].z == bhq[qg]) ? -1e9f : S[qg][mt][2];
                float v3 = (bp4[mt].w == bhq[qg]) ? -1e9f : S[qg][mt][3];
                S[qg][mt][0] = v0; S[qg][mt][1] = v1; S[qg][mt][2] = v2; S[qg][mt][3] = v3;
                m = fmaxf(m, fmaxf(fmaxf(v0, v1), fmaxf(v2, v3)));
            }
            pmax[qg] = m;
        }
        bool ng = __all((pmax[0] <= m_run[0] + 8.f) && (pmax[1] <= m_run[1] + 8.f));
        if (!ng) {   // rare: true cross-lane max + rescale
#pragma unroll
            for (int qg = 0; qg < 2; qg++) {
                float mq = fmaxf(pmax[qg], m_run[qg]);
                mq = fmaxf(mq, __shfl_xor(mq, 16));
                mq = fmaxf(mq, __shfl_xor(mq, 32));
                float f = exp2f(m_run[qg] - mq);
                m_run[qg] = mq;
                l_run[qg] *= f;
                float fr0 = __shfl(f, 4 * g + 0);
                float fr1 = __shfl(f, 4 * g + 1);
                float fr2 = __shfl(f, 4 * g + 2);
                float fr3 = __shfl(f, 4 * g + 3);
#pragma unroll
                for (int nt = 0; nt < 12; nt++) {
                    Ofr[qg][nt][0] *= fr0; Ofr[qg][nt][1] *= fr1;
                    Ofr[qg][nt][2] *= fr2; Ofr[qg][nt][3] *= fr3;
                }
            }
        }

        // ---- exp2 + per-lane partial l + pack P ----
        uint2 P2[2][4];
#pragma unroll
        for (int qg = 0; qg < 2; qg++) {
            float lsum = 0.f;
#pragma unroll
            for (int mt = 0; mt < 4; mt++) {
                float e0 = exp2f(S[qg][mt][0] - m_run[qg]);
                float e1 = exp2f(S[qg][mt][1] - m_run[qg]);
                float e2 = exp2f(S[qg][mt][2] - m_run[qg]);
                float e3 = exp2f(S[qg][mt][3] - m_run[qg]);
                lsum += (e0 + e1) + (e2 + e3);
                P2[qg][mt].x = pkbf(e0, e1);
                P2[qg][mt].y = pkbf(e2, e3);
            }
            l_run[qg] += lsum;
        }

        // ---- O += P·V, P redistributed in-register ----
#pragma unroll
        for (int ks = 0; ks < 2; ks++) {
            short8 pf0 = mkfrag(P2[0][2 * ks], P2[0][2 * ks + 1], hi, godd);
            short8 pf1 = mkfrag(P2[1][2 * ks], P2[1][2 * ks + 1], hi, godd);
            __builtin_amdgcn_s_setprio(1);
#pragma unroll
            for (int nt = 0; nt < 12; nt++) {
                short8 vf = *(const short8*)(Vc + (nt * 16 + lq) * 128 + ((ks * 64 + g * 16) ^ lqm));
                Ofr[0][nt] = __builtin_amdgcn_mfma_f32_16x16x32_bf16(pf0, vf, Ofr[0][nt], 0, 0, 0);
                Ofr[1][nt] = __builtin_amdgcn_mfma_f32_16x16x32_bf16(pf1, vf, Ofr[1][nt], 0, 0, 0);
            }
            __builtin_amdgcn_s_setprio(0);
        }

        // single per-tile sync: own prefetch had the whole tile to land
        asm volatile("s_waitcnt vmcnt(0)" ::: "memory");
        __builtin_amdgcn_s_barrier();
        cur ^= 1;
    }

    // ---- reduce per-lane l partials to per-query totals ----
    float lt[2];
#pragma unroll
    for (int qg = 0; qg < 2; qg++) {
        float l = l_run[qg];
        l += __shfl_xor(l, 16);
        l += __shfl_xor(l, 32);
        lt[qg] = l;
    }

    // ---- in-block merge of the two key streams ----
    const int tq = wq * 64 + lane;                 // 0..255 within quad
    float* mOf = (float*)smem;                     // [256][96]
    float* mls = (float*)(smem + 98304);           // [64][4]
    if (o == 1) {
#pragma unroll
        for (int qg = 0; qg < 2; qg++) {
#pragma unroll
            for (int nt = 0; nt < 12; nt++)
                *(f32x4*)(mOf + tq * 96 + qg * 48 + nt * 4) = Ofr[qg][nt];
            if (g == 0) {
                mls[(wq * 16 + lq) * 4 + qg * 2 + 0] = m_run[qg];
                mls[(wq * 16 + lq) * 4 + qg * 2 + 1] = lt[qg];
            }
        }
    }
    __syncthreads();
    if (o == 0) {
        const size_t plane = (size_t)(s * 4 + h) * 4096;
#pragma unroll
        for (int qg = 0; qg < 2; qg++) {
            float m1 = mls[(wq * 16 + lq) * 4 + qg * 2 + 0];
            float l1 = mls[(wq * 16 + lq) * 4 + qg * 2 + 1];
            float m = fmaxf(m_run[qg], m1);
            float a0 = exp2f(m_run[qg] - m), a1 = exp2f(m1 - m);
            float l = lt[qg] * a0 + l1 * a1;
            int qrow = n0 + wq * 32 + qg * 16;
            if (g == 0) {
                ml[(plane + qrow + lq) * 2 + 0] = m;
                ml[(plane + qrow + lq) * 2 + 1] = l;
            }
            float f0[4], f1[4];
#pragma unroll
            for (int j = 0; j < 4; j++) {
                f0[j] = __shfl(a0, 4 * g + j);
                f1[j] = __shfl(a1, 4 * g + j);
            }
#pragma unroll
            for (int nt = 0; nt < 12; nt++) {
                f32x4 o1 = *(f32x4*)(mOf + tq * 96 + qg * 48 + nt * 4);
#pragma unroll
                for (int j = 0; j < 4; j++) {
                    float val = Ofr[qg][nt][j] * f0[j] + o1[j] * f1[j];
                    Opart[(plane + qrow + 4 * g + j) * 192 + nt * 16 + lq] = f2bu(val);
                }
            }
        }
    }
}

// ============== combine outer key-split + build feats tail ==============
__global__ __launch_bounds__(256) void combine_feats(
    const ushort_t* __restrict__ Opart, const float* __restrict__ ml,
    const float* __restrict__ lhs_h, ushort_t* __restrict__ feats)
{
    const int t = threadIdx.x;
#pragma unroll
    for (int i = 0; i < 4; i++) {
        int q = blockIdx.x * 4 + i;
#pragma unroll
        for (int it = 0; it < 3; it++) {
            int c = t + it * 256;
            int h = c / 192, vd = c - h * 192;
            size_t i0 = (size_t)h * 4096 + q;
            size_t i1 = (size_t)(4 + h) * 4096 + q;
            float m0 = ml[i0 * 2], l0 = ml[i0 * 2 + 1];
            float m1 = ml[i1 * 2], l1 = ml[i1 * 2 + 1];
            float m = fmaxf(m0, m1);
            float e0 = exp2f(m0 - m), e1 = exp2f(m1 - m);
            float linv = 1.f / (l0 * e0 + l1 * e1);
            float O = (b2f(Opart[i0 * 192 + vd]) * e0 + b2f(Opart[i1 * 192 + vd]) * e1) * linv;
            feats[(size_t)q * 1280 + 512 + c] = f2bu(lhs_h[(size_t)q * 768 + c] - O);
        }
    }
}

// ================= h2 = h1 @ W2 (f32) + LayerNorm(128) ======================
__global__ __launch_bounds__(256) void h2_ln(
    const ushort_t* __restrict__ h1, const float* __restrict__ W2,
    const float* __restrict__ ln_g, const float* __restrict__ ln_b,
    float* __restrict__ h2out)
{
    const int n0 = blockIdx.x * 8;
    const int t = threadIdx.x;
    __shared__ float h1s[8][256];
    __shared__ float h2s[8][128];

#pragma unroll
    for (int i = 0; i < 8; i++) {
        int idx = t + i * 256; int r = idx >> 8, c = idx & 255;
        h1s[r][c] = b2f(h1[(size_t)(n0 + r) * 256 + c]);
    }
    __syncthreads();

    {
        int o2 = t & 127, gq = t >> 7;
        float acc[4] = {};
        for (int k4 = 0; k4 < 64; k4++) {
            float w0 = W2[(size_t)(k4 * 4 + 0) * 128 + o2];
            float w1 = W2[(size_t)(k4 * 4 + 1) * 128 + o2];
            float w2 = W2[(size_t)(k4 * 4 + 2) * 128 + o2];
            float w3 = W2[(size_t)(k4 * 4 + 3) * 128 + o2];
#pragma unroll
            for (int q = 0; q < 4; q++) {
                float4 hh = *(const float4*)&h1s[gq * 4 + q][k4 * 4];
                acc[q] += hh.x * w0 + hh.y * w1 + hh.z * w2 + hh.w * w3;
            }
        }
#pragma unroll
        for (int q = 0; q < 4; q++) h2s[gq * 4 + q][o2] = acc[q];
    }
    __syncthreads();

    {
        int wv = t >> 6, lane = t & 63;
#pragma unroll
        for (int sx = 0; sx < 2; sx++) {
            int nd = wv * 2 + sx;
            float x0 = h2s[nd][lane], x1 = h2s[nd][lane + 64];
            float sum = x0 + x1;
#pragma unroll
            for (int off = 32; off; off >>= 1) sum += __shfl_xor(sum, off);
            float mu = sum * (1.f / 128.f);
            float d0 = x0 - mu, d1 = x1 - mu;
            float s2 = d0 * d0 + d1 * d1;
#pragma unroll
            for (int off = 32; off; off >>= 1) s2 += __shfl_xor(s2, off);
            float rstd = rsqrtf(s2 * (1.f / 128.f) + 1e-5f);
            size_t base = (size_t)(n0 + nd) * 128;
            h2out[base + lane]      = d0 * rstd * ln_g[lane] + ln_b[lane];
            h2out[base + lane + 64] = d1 * rstd * ln_g[lane + 64] + ln_b[lane + 64];
        }
    }
}

// ============ pool (mean per graph, binary-search ranges) + classifier ======
__global__ __launch_bounds__(128) void pool_cls(
    const float* __restrict__ h2, const int* __restrict__ batch_h,
    const float* __restrict__ Wc, const float* __restrict__ bc,
    float* __restrict__ out)
{
    int b = blockIdx.x, t = threadIdx.x;
    __shared__ int bounds[2];
    if (t < 2) {
        int target = b + t;
        int lo = 0, hi = NH_N;
        while (lo < hi) {
            int mid = (lo + hi) >> 1;
            if (batch_h[mid] < target) lo = mid + 1; else hi = mid;
        }
        bounds[t] = lo;
    }
    __syncthreads();
    int s = bounds[0], e = bounds[1];
    float acc = 0.f;
    for (int n = s; n < e; n++) acc += h2[(size_t)n * 128 + t];
    float pooled = acc / fmaxf((float)(e - s), 1.f);
    __shared__ float red[128];
    for (int c = 0; c < 3; c++) {
        red[t] = pooled * Wc[t * 3 + c];
        __syncthreads();
        for (int off = 64; off > 0; off >>= 1) {
            if (t < off) red[t] += red[t + off];
            __syncthreads();
        }
        if (t == 0) out[b * 3 + c] = red[0] + bc[c];
        __syncthreads();
    }
}

// ---------------------------------------------------------------------------
extern "C" void kernel_launch(void* const* d_in, const int* in_sizes, int n_in,
                              void* d_out, int out_size, void* d_ws, size_t ws_size,
                              hipStream_t stream)
{
    const float* ctx_p  = (const float*)d_in[0];
    const float* ctx_h  = (const float*)d_in[1];
    const float* lhs_p  = (const float*)d_in[2];
    const float* lhs_h  = (const float*)d_in[3];
    const int*   batch_p = (const int*)d_in[4];
    const int*   batch_h = (const int*)d_in[5];
    const float* Wq = (const float*)d_in[6];
    const float* bq = (const float*)d_in[7];
    const float* Wk = (const float*)d_in[8];
    const float* bk = (const float*)d_in[9];
    const float* Wv = (const float*)d_in[10];
    const float* bv = (const float*)d_in[11];
    const float* W1 = (const float*)d_in[12];
    const float* b1 = (const float*)d_in[13];
    const float* W2 = (const float*)d_in[14];
    const float* ln_g = (const float*)d_in[15];
    const float* ln_b = (const float*)d_in[16];
    const float* Wc = (const float*)d_in[17];
    const float* bc = (const float*)d_in[18];
    float* out = (float*)d_out;

    // ---- workspace layout (ushort units unless noted) ----
    ushort_t* u = (ushort_t*)d_ws;
    ushort_t* ctxp_bf = u;                         // 2097152
    ushort_t* lhsp_bf = ctxp_bf + 2097152;         // 3145728
    ushort_t* Wqt  = lhsp_bf + 3145728;            // 262144
    ushort_t* Wkt  = Wqt + 262144;                 // 262144
    ushort_t* Wvt  = Wkt + 262144;                 // 589824
    ushort_t* Opart = u;                           // ALIAS: 6291456 over [ctxp..Wvt]
    ushort_t* W1t  = Wvt + 589824;                 // 327680
    ushort_t* Qb   = W1t + 327680;                 // 2097152
    ushort_t* Kb   = Qb + 2097152;                 // 2097152
    ushort_t* Vtb  = Kb + 2097152;                 // 3145728
    ushort_t* feats = Vtb + 3145728;               // 5242880
    ushort_t* h1   = feats + 5242880;              // 1048576
    float* ml  = (float*)(h1 + 1048576);           // 65536 f32
    float* h2  = ml + 65536;                       // 524288 f32
    float* bqp = h2 + 524288;                      // 512
    float* bkp = bqp + 512;                        // 512

    convert_all<<<800, 256, 0, stream>>>(
        ctx_h, ctx_p, lhs_p, Wq, Wk, Wv, W1, bq, bk,
        ctxp_bf, lhsp_bf, feats, Wqt, Wkt, Wvt, W1t, bqp, bkp);

    gemm_qkv<<<1792, 256, 0, stream>>>(
        feats, ctxp_bf, Wqt, Wkt, Wvt, lhsp_bf, bqp, bkp, bv, Qb, Kb, Vtb);

    attn_mfma<<<256, 512, 0, stream>>>(Qb, Kb, Vtb, batch_h, batch_p, Opart, ml);

    combine_feats<<<1024, 256, 0, stream>>>(Opart, ml, lhs_h, feats);

    gemm_mlp1<<<dim3(4, 64), 256, 0, stream>>>(feats, 1280, W1t, b1, h1, NH_N, 256, 1280);

    h2_ln<<<512, 256, 0, stream>>>(h1, W2, ln_g, ln_b, h2);
    pool_cls<<<B_N, 128, 0, stream>>>(h2, batch_h, Wc, bc, out);
}